// Round 1
// baseline (799.499 us; speedup 1.0000x reference)
//
#include <hip/hip_runtime.h>
#include <stdint.h>
#include <stddef.h>

// ---------------- problem constants ----------------
#define BB 2
#define SS 2048
#define DD 4096
#define NH 32
#define NKV 8
#define HD 128
#define QDIM 4096
#define KVDIM 1024
#define NQKV 6144
#define QK_SCALE 0.08838834764831843f  // 1/sqrt(128)

typedef __bf16 bf16;
typedef __bf16 bf16x8 __attribute__((ext_vector_type(8)));
typedef __bf16 bf16x4 __attribute__((ext_vector_type(4)));
typedef float f32x4 __attribute__((ext_vector_type(4)));

#define MFMA16(a, b, c) __builtin_amdgcn_mfma_f32_16x16x32_bf16((a), (b), (c), 0, 0, 0)

typedef __attribute__((address_space(1))) void GASV;
typedef __attribute__((address_space(3))) void LASV;

__device__ __forceinline__ void gload_lds16(const void* g, void* l) {
    // async global->LDS, 16B per lane; LDS dest = wave-uniform base + lane*16
    __builtin_amdgcn_global_load_lds((GASV*)g, (LASV*)l, 16, 0, 0);
}

// ---------------- fp32 -> bf16 convert (x) ----------------
__global__ __launch_bounds__(256) void k_cvt_x(const float* __restrict__ in,
                                               bf16* __restrict__ out) {
    size_t i = ((size_t)blockIdx.x * 256 + threadIdx.x) * 8;
    const float4 a = *(const float4*)(in + i);
    const float4 b = *(const float4*)(in + i + 4);
    bf16x8 v;
    v[0] = (bf16)a.x; v[1] = (bf16)a.y; v[2] = (bf16)a.z; v[3] = (bf16)a.w;
    v[4] = (bf16)b.x; v[5] = (bf16)b.y; v[6] = (bf16)b.z; v[7] = (bf16)b.w;
    *(bf16x8*)(out + i) = v;
}

// ---------------- transpose + convert: in[R][C] f32 -> out[C][R] bf16 ----------------
__global__ __launch_bounds__(256) void k_tr_cvt(const float* __restrict__ in,
                                                bf16* __restrict__ out, int R, int C) {
    __shared__ float tile[64][65];
    const int t = threadIdx.x;
    const int tx = t & 15, ty = t >> 4;
    const int r0 = blockIdx.y * 64, c0 = blockIdx.x * 64;
#pragma unroll
    for (int p = 0; p < 4; ++p) {
        const float4 v = *(const float4*)(in + (size_t)(r0 + p * 16 + ty) * C + c0 + tx * 4);
        tile[p * 16 + ty][tx * 4 + 0] = v.x;
        tile[p * 16 + ty][tx * 4 + 1] = v.y;
        tile[p * 16 + ty][tx * 4 + 2] = v.z;
        tile[p * 16 + ty][tx * 4 + 3] = v.w;
    }
    __syncthreads();
#pragma unroll
    for (int p = 0; p < 4; ++p) {
        const int oc = c0 + p * 16 + ty;
        bf16x4 pk;
#pragma unroll
        for (int j = 0; j < 4; ++j) pk[j] = (bf16)tile[tx * 4 + j][p * 16 + ty];
        *(bf16x4*)(out + (size_t)oc * R + r0 + tx * 4) = pk;
    }
}

// ---------------- GEMM core: 128x128 tile, BK=64, XOR-8 swizzled LDS ----------------
// Stages a [128 rows][64 k] bf16 tile (16KB). LDS is written linearly by
// global_load_lds; the 16B-chunk XOR swizzle is applied by pre-swizzling the
// per-lane GLOBAL source address (m173 pattern). chunk' = chunk ^ (row&7).
__device__ __forceinline__ void stage_tile64(bf16* lds, const bf16* gbase, int ld, int kt) {
    const int tid = threadIdx.x;
    const int lane = tid & 63;
    const int w = tid >> 6;
#pragma unroll
    for (int i = 0; i < 4; ++i) {
        const int phys = i * 4096 + w * 1024 + lane * 16;   // byte offset in tile
        const int row = phys >> 7;                          // 128B per row
        const int cc = (phys >> 4) & 7;
        const int lc = cc ^ (row & 7);
        gload_lds16(gbase + (size_t)row * ld + kt + lc * 8,
                    (char*)lds + (i * 4096 + w * 1024));
    }
}

__device__ __forceinline__ void gemm_main(const bf16* __restrict__ Atile,
                                          const bf16* __restrict__ Btile,
                                          bf16* As, bf16* Bs, f32x4 acc[4][4]) {
    const int tid = threadIdx.x, lane = tid & 63, w = tid >> 6;
    const int wm = (w >> 1) * 64, wn = (w & 1) * 64;
    const int l15 = lane & 15, l4 = lane >> 4;
    const f32x4 vz = {0.f, 0.f, 0.f, 0.f};
#pragma unroll
    for (int m = 0; m < 4; ++m)
#pragma unroll
        for (int n = 0; n < 4; ++n) acc[m][n] = vz;

    for (int kt = 0; kt < 4096; kt += 64) {
        __syncthreads();                 // protect LDS from previous iteration's readers
        stage_tile64(As, Atile, 4096, kt);
        stage_tile64(Bs, Btile, 4096, kt);
        __syncthreads();                 // compiler drains vmcnt(0) before barrier
#pragma unroll
        for (int kc = 0; kc < 2; ++kc) {
            bf16x8 af[4], bfr[4];
#pragma unroll
            for (int m = 0; m < 4; ++m) {
                const int row = wm + m * 16 + l15;
                const int cc = kc * 4 + l4;
                af[m] = *(const bf16x8*)((const char*)As + (row << 7) + ((cc ^ (row & 7)) << 4));
            }
#pragma unroll
            for (int n = 0; n < 4; ++n) {
                const int row = wn + n * 16 + l15;
                const int cc = kc * 4 + l4;
                bfr[n] = *(const bf16x8*)((const char*)Bs + (row << 7) + ((cc ^ (row & 7)) << 4));
            }
#pragma unroll
            for (int m = 0; m < 4; ++m)
#pragma unroll
                for (int n = 0; n < 4; ++n) acc[m][n] = MFMA16(af[m], bfr[n], acc[m][n]);
        }
    }
}

// ---------------- GEMM 1: xqkv = x @ wqkv, fused RoPE, writes Q,K,V^T bf16 ----------------
__global__ __launch_bounds__(256) void k_gemm_qkv(const bf16* __restrict__ A,
                                                  const bf16* __restrict__ Bt,
                                                  const float* __restrict__ fc,
                                                  bf16* __restrict__ Qb,
                                                  bf16* __restrict__ Kb,
                                                  bf16* __restrict__ VTb) {
    __shared__ __align__(16) bf16 As[128 * 64];
    __shared__ __align__(16) bf16 Bs[128 * 64];
    f32x4 acc[4][4];
    const int bx = blockIdx.x, by = blockIdx.y;
    gemm_main(A + (size_t)by * 128 * 4096, Bt + (size_t)bx * 128 * 4096, As, Bs, acc);

    const int tid = threadIdx.x, lane = tid & 63, w = tid >> 6;
    const int wm = (w >> 1) * 64, wn = (w & 1) * 64, l15 = lane & 15, l4 = lane >> 4;
    const int n0 = bx * 128 + wn;   // uniform per block (regions are 128-aligned)
#pragma unroll
    for (int m = 0; m < 4; ++m) {
        const int rowbase = by * 128 + wm + m * 16 + l4 * 4;
#pragma unroll
        for (int n = 0; n < 4; ++n) {
            const int col = n0 + n * 16 + l15;
            f32x4 v = acc[m][n];
            if (n0 < QDIM + KVDIM) {
                // Q or K: apply RoPE. Paired column col^1 lives in lane^1 (C-layout col=lane&15).
                const int d = col & (HD - 1);
                const int dp = d & ~1;
                const float sgn = (d & 1) ? 1.f : -1.f;
#pragma unroll
                for (int r = 0; r < 4; ++r) {
                    const int row = rowbase + r;
                    const int s = row & (SS - 1);
                    const float2 sc = *(const float2*)(fc + s * HD + dp);  // (sin, cos)
                    const float partner = __shfl_xor(v[r], 1);
                    float res = v[r] * sc.y + sgn * partner * sc.x;
                    if (n0 < QDIM) {
                        res *= QK_SCALE;  // fold 1/sqrt(hd) into Q
                        Qb[(size_t)row * QDIM + col] = (bf16)res;
                    } else {
                        Kb[(size_t)row * KVDIM + (col - QDIM)] = (bf16)res;
                    }
                }
            } else {
                // V: write transposed [b][kvh][d][s]; lane's 4 rows are consecutive s -> 8B store
                const int hdv = col - (QDIM + KVDIM);
                const int kvh = hdv >> 7, dd = hdv & (HD - 1);
                const int bb = rowbase >> 11, s = rowbase & (SS - 1);
                bf16x4 pk;
#pragma unroll
                for (int r = 0; r < 4; ++r) pk[r] = (bf16)v[r];
                *(bf16x4*)(VTb + ((size_t)((bb * NKV + kvh) * HD + dd)) * SS + s) = pk;
            }
        }
    }
}

// ---------------- flash attention: 1 block per (b,h,64-row q tile), 4 waves ----------------
__global__ __launch_bounds__(256) void k_attn(const bf16* __restrict__ Qb,
                                              const bf16* __restrict__ Kb,
                                              const bf16* __restrict__ VTb,
                                              bf16* __restrict__ Ob) {
    __shared__ __align__(16) bf16 Ks[64 * 128];   // [kv][d], XOR-8 swizzled 16B chunks
    __shared__ __align__(16) bf16 Vs[128 * 64];   // [d][kv] (V^T), XOR-8 swizzled
    __shared__ __align__(16) bf16 Ps[4][16 * 88]; // per-wave P, 176B row stride (2-way = free)
    const int qt = blockIdx.x, h = blockIdx.y, b = blockIdx.z;
    const int kvh = h >> 2;
    const int tid = threadIdx.x, lane = tid & 63, w = tid >> 6;
    const int l15 = lane & 15, l4 = lane >> 4;
    const int q0 = qt * 64;

    // Q fragments in registers (A-operand: row = lane&15, k = (lane>>4)*8 contiguous)
    const int qrow = q0 + w * 16 + l15;
    bf16x8 qf[4];
    const bf16* qbase = Qb + ((size_t)(b * SS + qrow) << 12) + h * HD + l4 * 8;
#pragma unroll
    for (int kc = 0; kc < 4; ++kc) qf[kc] = *(const bf16x8*)(qbase + kc * 32);

    const f32x4 vz = {0.f, 0.f, 0.f, 0.f};
    f32x4 o[8];
#pragma unroll
    for (int df = 0; df < 8; ++df) o[df] = vz;
    float m_run[4] = {-1e30f, -1e30f, -1e30f, -1e30f};
    float l_run[4] = {0.f, 0.f, 0.f, 0.f};

    const int nt = qt + 1;  // causal: only tiles up to the diagonal
    for (int t = 0; t < nt; ++t) {
        __syncthreads();
        // stage K tile [64][128] (rows 256B = 16 chunks, chunk' = chunk ^ (row&7))
#pragma unroll
        for (int i = 0; i < 4; ++i) {
            const int phys = (w * 4 + i) * 1024 + lane * 16;
            const int row = phys >> 8;
            const int cc = (phys >> 4) & 15;
            const int lc = cc ^ (row & 7);
            gload_lds16(Kb + (size_t)(b * SS + t * 64 + row) * KVDIM + kvh * HD + lc * 8,
                        (char*)Ks + (w * 4 + i) * 1024);
        }
        // stage V^T tile [128][64] (rows 128B = 8 chunks)
#pragma unroll
        for (int i = 0; i < 4; ++i) {
            const int phys = (w * 4 + i) * 1024 + lane * 16;
            const int row = phys >> 7;
            const int cc = (phys >> 4) & 7;
            const int lc = cc ^ (row & 7);
            gload_lds16(VTb + ((size_t)((b * NKV + kvh) * HD + row)) * SS + t * 64 + lc * 8,
                        (char*)Vs + (w * 4 + i) * 1024);
        }
        __syncthreads();

        // S = Q K^T  (16 q-rows x 64 kv), Q pre-scaled by 1/sqrt(hd)
        f32x4 sa[4];
#pragma unroll
        for (int n = 0; n < 4; ++n) sa[n] = vz;
#pragma unroll
        for (int kc = 0; kc < 4; ++kc) {
#pragma unroll
            for (int n = 0; n < 4; ++n) {
                const int krow = n * 16 + l15;
                const int cc = kc * 4 + l4;
                const bf16x8 kf =
                    *(const bf16x8*)((const char*)Ks + (krow << 8) + ((cc ^ (krow & 7)) << 4));
                sa[n] = MFMA16(qf[kc], kf, sa[n]);
            }
        }

        if (t == qt) {  // diagonal tile: causal mask
#pragma unroll
            for (int n = 0; n < 4; ++n)
#pragma unroll
                for (int r = 0; r < 4; ++r) {
                    const int col = t * 64 + n * 16 + l15;
                    const int qr = q0 + w * 16 + l4 * 4 + r;
                    if (col > qr) sa[n][r] = -1e30f;
                }
        }

        // wave-parallel online softmax (row = 16 lanes sharing l>>4; reduce over l&15)
        float alpha[4];
#pragma unroll
        for (int r = 0; r < 4; ++r) {
            float mx = fmaxf(fmaxf(sa[0][r], sa[1][r]), fmaxf(sa[2][r], sa[3][r]));
#pragma unroll
            for (int mk = 1; mk <= 8; mk <<= 1) mx = fmaxf(mx, __shfl_xor(mx, mk));
            const float mn = fmaxf(m_run[r], mx);
            alpha[r] = __expf(m_run[r] - mn);
            m_run[r] = mn;
            float rs = 0.f;
#pragma unroll
            for (int n = 0; n < 4; ++n) {
                const float p = __expf(sa[n][r] - mn);
                sa[n][r] = p;
                rs += p;
            }
#pragma unroll
            for (int mk = 1; mk <= 8; mk <<= 1) rs += __shfl_xor(rs, mk);
            l_run[r] = l_run[r] * alpha[r] + rs;
        }
#pragma unroll
        for (int df = 0; df < 8; ++df)
#pragma unroll
            for (int r = 0; r < 4; ++r) o[df][r] *= alpha[r];

        // P -> LDS (per-wave buffer) to re-layout into PV A-operand fragments
#pragma unroll
        for (int n = 0; n < 4; ++n)
#pragma unroll
            for (int r = 0; r < 4; ++r)
                Ps[w][(l4 * 4 + r) * 88 + n * 16 + l15] = (bf16)sa[n][r];
        __syncthreads();

        // O += P V
#pragma unroll
        for (int ks = 0; ks < 2; ++ks) {
            const bf16x8 pf = *(const bf16x8*)(&Ps[w][l15 * 88 + ks * 32 + l4 * 8]);
#pragma unroll
            for (int df = 0; df < 8; ++df) {
                const int vrow = df * 16 + l15;
                const int cc = ks * 4 + l4;
                const bf16x8 vf =
                    *(const bf16x8*)((const char*)Vs + (vrow << 7) + ((cc ^ (vrow & 7)) << 4));
                o[df] = MFMA16(pf, vf, o[df]);
            }
        }
    }

    float inv[4];
#pragma unroll
    for (int r = 0; r < 4; ++r) inv[r] = 1.f / l_run[r];
#pragma unroll
    for (int df = 0; df < 8; ++df)
#pragma unroll
        for (int r = 0; r < 4; ++r) {
            const size_t row = (size_t)(b * SS + q0 + w * 16 + l4 * 4 + r);
            Ob[(row << 12) + h * HD + df * 16 + l15] = (bf16)(o[df][r] * inv[r]);
        }
}

// ---------------- GEMM 2: out = attn @ wo (f32 output) ----------------
__global__ __launch_bounds__(256) void k_gemm_out(const bf16* __restrict__ A,
                                                  const bf16* __restrict__ Bt,
                                                  float* __restrict__ out) {
    __shared__ __align__(16) bf16 As[128 * 64];
    __shared__ __align__(16) bf16 Bs[128 * 64];
    f32x4 acc[4][4];
    const int bx = blockIdx.x, by = blockIdx.y;
    gemm_main(A + (size_t)by * 128 * 4096, Bt + (size_t)bx * 128 * 4096, As, Bs, acc);

    const int tid = threadIdx.x, lane = tid & 63, w = tid >> 6;
    const int wm = (w >> 1) * 64, wn = (w & 1) * 64, l15 = lane & 15, l4 = lane >> 4;
#pragma unroll
    for (int m = 0; m < 4; ++m) {
        const int row = by * 128 + wm + m * 16 + l4 * 4;
#pragma unroll
        for (int n = 0; n < 4; ++n) {
            const int col = bx * 128 + wn + n * 16 + l15;
#pragma unroll
            for (int r = 0; r < 4; ++r) out[(size_t)(row + r) * DD + col] = acc[m][n][r];
        }
    }
}

// ---------------- launcher ----------------
extern "C" void kernel_launch(void* const* d_in, const int* in_sizes, int n_in,
                              void* d_out, int out_size, void* d_ws, size_t ws_size,
                              hipStream_t stream) {
    const float* x    = (const float*)d_in[0];
    const float* fc   = (const float*)d_in[1];
    const float* wqkv = (const float*)d_in[2];
    const float* wo   = (const float*)d_in[3];
    // is_causal (d_in[4]) is always 1 per setup_inputs; causality is baked in.

    char* wsp = (char*)d_ws;
    const size_t MB = (size_t)1 << 20;
    bf16* xb    = (bf16*)(wsp);              // 32MB: x bf16; reused as attn-out after gemm_qkv
    bf16* wqkvT = (bf16*)(wsp + 32 * MB);    // 48MB: wqkv^T bf16 [6144][4096]
    bf16* woT   = (bf16*)(wsp + 32 * MB);    // 32MB: wo^T bf16 (aliases wqkvT; written after gemm_qkv)
    bf16* Qb    = (bf16*)(wsp + 80 * MB);    // 32MB: Q (rope+scaled) [B*S][4096]
    bf16* Kb    = (bf16*)(wsp + 112 * MB);   //  8MB: K (rope) [B*S][1024]
    bf16* VTb   = (bf16*)(wsp + 120 * MB);   //  8MB: V^T [B][8][128][2048]
    bf16* Ab    = (bf16*)(wsp);              // attn output bf16 [B*S][4096] (aliases xb)
    float* out  = (float*)d_out;

    k_cvt_x<<<8192, 256, 0, stream>>>(x, xb);
    k_tr_cvt<<<dim3(NQKV / 64, DD / 64), 256, 0, stream>>>(wqkv, wqkvT, DD, NQKV);
    k_gemm_qkv<<<dim3(NQKV / 128, (BB * SS) / 128), 256, 0, stream>>>(xb, wqkvT, fc, Qb, Kb, VTb);
    k_tr_cvt<<<dim3(DD / 64, QDIM / 64), 256, 0, stream>>>(wo, woT, QDIM, DD);
    k_attn<<<dim3(SS / 64, NH, BB), 256, 0, stream>>>(Qb, Kb, VTb, Ab);
    k_gemm_out<<<dim3(DD / 128, (BB * SS) / 128), 256, 0, stream>>>(Ab, woT, out);
}

// Round 2
// 662.517 us; speedup vs baseline: 1.2068x; 1.2068x over previous
//
#include <hip/hip_runtime.h>
#include <stdint.h>
#include <stddef.h>

// ---------------- problem constants ----------------
#define BB 2
#define SS 2048
#define DD 4096
#define NH 32
#define NKV 8
#define HD 128
#define QDIM 4096
#define KVDIM 1024
#define NQKV 6144
// 1/sqrt(128) * log2(e): Q pre-scale so softmax exp is a single v_exp_f32 (2^x)
#define QK_SCALE_L2E 0.12751744f

typedef __bf16 bf16;
typedef __bf16 bf16x8 __attribute__((ext_vector_type(8)));
typedef __bf16 bf16x4 __attribute__((ext_vector_type(4)));
typedef float f32x4 __attribute__((ext_vector_type(4)));

#define MFMA16(a, b, c) __builtin_amdgcn_mfma_f32_16x16x32_bf16((a), (b), (c), 0, 0, 0)

typedef __attribute__((address_space(1))) void GASV;
typedef __attribute__((address_space(3))) void LASV;

__device__ __forceinline__ void gload_lds16(const void* g, void* l) {
    __builtin_amdgcn_global_load_lds((GASV*)g, (LASV*)l, 16, 0, 0);
}

__device__ __forceinline__ float fexp2(float x) {
    float r;
    asm("v_exp_f32 %0, %1" : "=v"(r) : "v"(x));
    return r;
}

// ---------------- fp32 -> bf16 convert (x) ----------------
__global__ __launch_bounds__(256) void k_cvt_x(const float* __restrict__ in,
                                               bf16* __restrict__ out) {
    size_t i = ((size_t)blockIdx.x * 256 + threadIdx.x) * 8;
    const float4 a = *(const float4*)(in + i);
    const float4 b = *(const float4*)(in + i + 4);
    bf16x8 v;
    v[0] = (bf16)a.x; v[1] = (bf16)a.y; v[2] = (bf16)a.z; v[3] = (bf16)a.w;
    v[4] = (bf16)b.x; v[5] = (bf16)b.y; v[6] = (bf16)b.z; v[7] = (bf16)b.w;
    *(bf16x8*)(out + i) = v;
}

// ---------------- transpose + convert: in[R][C] f32 -> out[C][R] bf16 ----------------
__global__ __launch_bounds__(256) void k_tr_cvt(const float* __restrict__ in,
                                                bf16* __restrict__ out, int R, int C) {
    __shared__ float tile[64][65];
    const int t = threadIdx.x;
    const int tx = t & 15, ty = t >> 4;
    const int r0 = blockIdx.y * 64, c0 = blockIdx.x * 64;
#pragma unroll
    for (int p = 0; p < 4; ++p) {
        const float4 v = *(const float4*)(in + (size_t)(r0 + p * 16 + ty) * C + c0 + tx * 4);
        tile[p * 16 + ty][tx * 4 + 0] = v.x;
        tile[p * 16 + ty][tx * 4 + 1] = v.y;
        tile[p * 16 + ty][tx * 4 + 2] = v.z;
        tile[p * 16 + ty][tx * 4 + 3] = v.w;
    }
    __syncthreads();
#pragma unroll
    for (int p = 0; p < 4; ++p) {
        const int oc = c0 + p * 16 + ty;
        bf16x4 pk;
#pragma unroll
        for (int j = 0; j < 4; ++j) pk[j] = (bf16)tile[tx * 4 + j][p * 16 + ty];
        *(bf16x4*)(out + (size_t)oc * R + r0 + tx * 4) = pk;
    }
}

// ---------------- GEMM core: 128x128 tile, BK=64, XOR-8 swizzled LDS ----------------
__device__ __forceinline__ void stage_tile64(bf16* lds, const bf16* gbase, int ld, int kt) {
    const int tid = threadIdx.x;
    const int lane = tid & 63;
    const int w = tid >> 6;
#pragma unroll
    for (int i = 0; i < 4; ++i) {
        const int phys = i * 4096 + w * 1024 + lane * 16;   // byte offset in tile
        const int row = phys >> 7;                          // 128B per row
        const int cc = (phys >> 4) & 7;
        const int lc = cc ^ (row & 7);
        gload_lds16(gbase + (size_t)row * ld + kt + lc * 8,
                    (char*)lds + (i * 4096 + w * 1024));
    }
}

__device__ __forceinline__ void gemm_main(const bf16* __restrict__ Atile,
                                          const bf16* __restrict__ Btile,
                                          bf16* As, bf16* Bs, f32x4 acc[4][4]) {
    const int tid = threadIdx.x, lane = tid & 63, w = tid >> 6;
    const int wm = (w >> 1) * 64, wn = (w & 1) * 64;
    const int l15 = lane & 15, l4 = lane >> 4;
    const f32x4 vz = {0.f, 0.f, 0.f, 0.f};
#pragma unroll
    for (int m = 0; m < 4; ++m)
#pragma unroll
        for (int n = 0; n < 4; ++n) acc[m][n] = vz;

    for (int kt = 0; kt < 4096; kt += 64) {
        __syncthreads();
        stage_tile64(As, Atile, 4096, kt);
        stage_tile64(Bs, Btile, 4096, kt);
        __syncthreads();
#pragma unroll
        for (int kc = 0; kc < 2; ++kc) {
            bf16x8 af[4], bfr[4];
#pragma unroll
            for (int m = 0; m < 4; ++m) {
                const int row = wm + m * 16 + l15;
                const int cc = kc * 4 + l4;
                af[m] = *(const bf16x8*)((const char*)As + (row << 7) + ((cc ^ (row & 7)) << 4));
            }
#pragma unroll
            for (int n = 0; n < 4; ++n) {
                const int row = wn + n * 16 + l15;
                const int cc = kc * 4 + l4;
                bfr[n] = *(const bf16x8*)((const char*)Bs + (row << 7) + ((cc ^ (row & 7)) << 4));
            }
#pragma unroll
            for (int m = 0; m < 4; ++m)
#pragma unroll
                for (int n = 0; n < 4; ++n) acc[m][n] = MFMA16(af[m], bfr[n], acc[m][n]);
        }
    }
}

// ---------------- GEMM 1: xqkv = x @ wqkv, fused RoPE, writes Q,K,V^T bf16 ----------------
__global__ __launch_bounds__(256) void k_gemm_qkv(const bf16* __restrict__ A,
                                                  const bf16* __restrict__ Bt,
                                                  const float* __restrict__ fc,
                                                  bf16* __restrict__ Qb,
                                                  bf16* __restrict__ Kb,
                                                  bf16* __restrict__ VTb) {
    __shared__ __align__(16) bf16 As[128 * 64];
    __shared__ __align__(16) bf16 Bs[128 * 64];
    f32x4 acc[4][4];
    const int bx = blockIdx.x, by = blockIdx.y;
    gemm_main(A + (size_t)by * 128 * 4096, Bt + (size_t)bx * 128 * 4096, As, Bs, acc);

    const int tid = threadIdx.x, lane = tid & 63, w = tid >> 6;
    const int wm = (w >> 1) * 64, wn = (w & 1) * 64, l15 = lane & 15, l4 = lane >> 4;
    const int n0 = bx * 128 + wn;
#pragma unroll
    for (int m = 0; m < 4; ++m) {
        const int rowbase = by * 128 + wm + m * 16 + l4 * 4;
#pragma unroll
        for (int n = 0; n < 4; ++n) {
            const int col = n0 + n * 16 + l15;
            f32x4 v = acc[m][n];
            if (n0 < QDIM + KVDIM) {
                const int d = col & (HD - 1);
                const int dp = d & ~1;
                const float sgn = (d & 1) ? 1.f : -1.f;
#pragma unroll
                for (int r = 0; r < 4; ++r) {
                    const int row = rowbase + r;
                    const int s = row & (SS - 1);
                    const float2 sc = *(const float2*)(fc + s * HD + dp);  // (sin, cos)
                    const float partner = __shfl_xor(v[r], 1);
                    float res = v[r] * sc.y + sgn * partner * sc.x;
                    if (n0 < QDIM) {
                        res *= QK_SCALE_L2E;  // fold 1/sqrt(hd) * log2(e) into Q
                        Qb[(size_t)row * QDIM + col] = (bf16)res;
                    } else {
                        Kb[(size_t)row * KVDIM + (col - QDIM)] = (bf16)res;
                    }
                }
            } else {
                const int hdv = col - (QDIM + KVDIM);
                const int kvh = hdv >> 7, dd = hdv & (HD - 1);
                const int bb = rowbase >> 11, s = rowbase & (SS - 1);
                bf16x4 pk;
#pragma unroll
                for (int r = 0; r < 4; ++r) pk[r] = (bf16)v[r];
                *(bf16x4*)(VTb + ((size_t)((bb * NKV + kvh) * HD + dd)) * SS + s) = pk;
            }
        }
    }
}

// ---------------- flash attention v2 ----------------
// Grid (8, NH, BB). Block = 256 thr / 4 waves. Block jj handles q-tiles {jj, 15-jj}
// (128 rows each) -> exactly 36 kv-iters per block, 512 blocks, 2/CU, all resident.
// Per wave: 32 q-rows (2 m-frags). K/V staged global->reg->LDS (T14 split): loads
// for tile t+1 issued before computing tile t; swizzled ds_write after the barrier.
__global__ __launch_bounds__(256, 2) void k_attn(const bf16* __restrict__ Qb,
                                                 const bf16* __restrict__ Kb,
                                                 const bf16* __restrict__ VTb,
                                                 bf16* __restrict__ Ob) {
    __shared__ __align__(16) bf16 Ks[64 * 128];    // [kv][d], XOR-8 swizzled 16B chunks
    __shared__ __align__(16) bf16 Vs[128 * 64];    // [d][kv] (V^T), XOR-8 swizzled
    __shared__ __align__(16) bf16 Ps[4][32 * 88];  // per-wave P (32 rows, 176B stride)
    const int jj = blockIdx.x, h = blockIdx.y, b = blockIdx.z;
    const int kvh = h >> 2;
    const int tid = threadIdx.x, lane = tid & 63, w = tid >> 6;
    const int l15 = lane & 15, l4 = lane >> 4;

    const bf16* Kg = Kb + (size_t)b * SS * KVDIM + kvh * HD;
    const bf16* Vg = VTb + (size_t)(b * NKV + kvh) * HD * SS;

    int4 kreg[4], vreg[4];
    const f32x4 vz = {0.f, 0.f, 0.f, 0.f};

    auto issue_kv = [&](int t) {
#pragma unroll
        for (int i = 0; i < 4; ++i) {
            const int off = i * 4096 + tid * 16;
            const int row = off >> 8;                     // 256B per K row
            const int cc = (off >> 4) & 15;
            kreg[i] = *(const int4*)((const char*)(Kg + (size_t)(t * 64 + row) * KVDIM) + cc * 16);
        }
#pragma unroll
        for (int i = 0; i < 4; ++i) {
            const int off = i * 4096 + tid * 16;
            const int row = off >> 7;                     // 128B per V^T row
            const int cc = (off >> 4) & 7;
            vreg[i] = *(const int4*)((const char*)(Vg + (size_t)row * SS + t * 64) + cc * 16);
        }
    };

#pragma unroll 1
    for (int pj = 0; pj < 2; ++pj) {
        const int j = pj ? (15 - jj) : jj;
        const int q0 = j * 128;
        const int nt = 2 * j + 2;

        // Q fragments for this q-tile (A-operand: row=lane&15, k=(lane>>4)*8)
        bf16x8 qf[2][4];
#pragma unroll
        for (int m = 0; m < 2; ++m) {
            const int qrow = q0 + w * 32 + m * 16 + l15;
            const bf16* qb = Qb + ((size_t)(b * SS + qrow) << 12) + h * HD + l4 * 8;
#pragma unroll
            for (int kc = 0; kc < 4; ++kc) qf[m][kc] = *(const bf16x8*)(qb + kc * 32);
        }

        f32x4 o[2][8];
#pragma unroll
        for (int m = 0; m < 2; ++m)
#pragma unroll
            for (int df = 0; df < 8; ++df) o[m][df] = vz;
        float m_run[2][4], l_run[2][4];
#pragma unroll
        for (int m = 0; m < 2; ++m)
#pragma unroll
            for (int r = 0; r < 4; ++r) { m_run[m][r] = -1e30f; l_run[m][r] = 0.f; }

        issue_kv(0);  // prologue prefetch

        for (int t = 0; t < nt; ++t) {
            __syncthreads();  // all waves done reading LDS of previous tile
            // write staged regs -> LDS (swizzle applied on write side)
#pragma unroll
            for (int i = 0; i < 4; ++i) {
                const int off = i * 4096 + tid * 16;
                const int row = off >> 8;
                const int cc = (off >> 4) & 15;
                const int lc = cc ^ (row & 7);
                *(int4*)((char*)Ks + row * 256 + lc * 16) = kreg[i];
            }
#pragma unroll
            for (int i = 0; i < 4; ++i) {
                const int off = i * 4096 + tid * 16;
                const int row = off >> 7;
                const int cc = (off >> 4) & 7;
                const int lc = cc ^ (row & 7);
                *(int4*)((char*)Vs + row * 128 + lc * 16) = vreg[i];
            }
            __syncthreads();  // K/V tile visible to all waves

            if (t + 1 < nt) issue_kv(t + 1);  // prefetch next tile under compute

            // S = Q K^T : 2 m-frags x 64 kv, K frag reused across m
            f32x4 sa[2][4];
#pragma unroll
            for (int m = 0; m < 2; ++m)
#pragma unroll
                for (int n = 0; n < 4; ++n) sa[m][n] = vz;
            __builtin_amdgcn_s_setprio(1);
#pragma unroll
            for (int kc = 0; kc < 4; ++kc)
#pragma unroll
                for (int n = 0; n < 4; ++n) {
                    const int krow = n * 16 + l15;
                    const int cc = kc * 4 + l4;
                    const bf16x8 kf =
                        *(const bf16x8*)((const char*)Ks + (krow << 8) + ((cc ^ (krow & 7)) << 4));
                    sa[0][n] = MFMA16(qf[0][kc], kf, sa[0][n]);
                    sa[1][n] = MFMA16(qf[1][kc], kf, sa[1][n]);
                }
            __builtin_amdgcn_s_setprio(0);

            if (t >= 2 * j) {  // causal mask (only the last two tiles straddle the diag)
#pragma unroll
                for (int m = 0; m < 2; ++m)
#pragma unroll
                    for (int n = 0; n < 4; ++n)
#pragma unroll
                        for (int r = 0; r < 4; ++r) {
                            const int col = t * 64 + n * 16 + l15;
                            const int qr = q0 + w * 32 + m * 16 + l4 * 4 + r;
                            if (col > qr) sa[m][n][r] = -1e30f;
                        }
            }

            // online softmax in log2 domain (scores pre-scaled by log2e)
#pragma unroll
            for (int m = 0; m < 2; ++m)
#pragma unroll
                for (int r = 0; r < 4; ++r) {
                    float mx = fmaxf(fmaxf(sa[m][0][r], sa[m][1][r]),
                                     fmaxf(sa[m][2][r], sa[m][3][r]));
#pragma unroll
                    for (int mk = 1; mk <= 8; mk <<= 1) mx = fmaxf(mx, __shfl_xor(mx, mk));
                    const float mn = fmaxf(m_run[m][r], mx);
                    const float alpha = fexp2(m_run[m][r] - mn);
                    m_run[m][r] = mn;
                    float rs = 0.f;
#pragma unroll
                    for (int n = 0; n < 4; ++n) {
                        const float p = fexp2(sa[m][n][r] - mn);
                        sa[m][n][r] = p;
                        rs += p;
                    }
#pragma unroll
                    for (int mk = 1; mk <= 8; mk <<= 1) rs += __shfl_xor(rs, mk);
                    l_run[m][r] = l_run[m][r] * alpha + rs;
#pragma unroll
                    for (int df = 0; df < 8; ++df) o[m][df][r] *= alpha;
                }

            // P -> per-wave LDS (no block barrier needed) -> A-operand fragments
#pragma unroll
            for (int m = 0; m < 2; ++m)
#pragma unroll
                for (int n = 0; n < 4; ++n)
#pragma unroll
                    for (int r = 0; r < 4; ++r)
                        Ps[w][(m * 16 + l4 * 4 + r) * 88 + n * 16 + l15] = (bf16)sa[m][n][r];

            bf16x8 pf0[2], pf1[2];
#pragma unroll
            for (int ks = 0; ks < 2; ++ks) {
                pf0[ks] = *(const bf16x8*)(&Ps[w][l15 * 88 + ks * 32 + l4 * 8]);
                pf1[ks] = *(const bf16x8*)(&Ps[w][(16 + l15) * 88 + ks * 32 + l4 * 8]);
            }

            // O += P V, V frag reused across m
            __builtin_amdgcn_s_setprio(1);
#pragma unroll
            for (int df = 0; df < 8; ++df)
#pragma unroll
                for (int ks = 0; ks < 2; ++ks) {
                    const int vrow = df * 16 + l15;
                    const int cc = ks * 4 + l4;
                    const bf16x8 vf =
                        *(const bf16x8*)((const char*)Vs + (vrow << 7) + ((cc ^ (vrow & 7)) << 4));
                    o[0][df] = MFMA16(pf0[ks], vf, o[0][df]);
                    o[1][df] = MFMA16(pf1[ks], vf, o[1][df]);
                }
            __builtin_amdgcn_s_setprio(0);
        }

        // epilogue: normalize and store this q-tile
#pragma unroll
        for (int m = 0; m < 2; ++m)
#pragma unroll
            for (int r = 0; r < 4; ++r) {
                const float inv = 1.f / l_run[m][r];
                const size_t row = (size_t)(b * SS + q0 + w * 32 + m * 16 + l4 * 4 + r);
#pragma unroll
                for (int df = 0; df < 8; ++df)
                    Ob[(row << 12) + h * HD + df * 16 + l15] = (bf16)(o[m][df][r] * inv);
            }
    }
}

// ---------------- GEMM 2: out = attn @ wo (f32 output) ----------------
__global__ __launch_bounds__(256) void k_gemm_out(const bf16* __restrict__ A,
                                                  const bf16* __restrict__ Bt,
                                                  float* __restrict__ out) {
    __shared__ __align__(16) bf16 As[128 * 64];
    __shared__ __align__(16) bf16 Bs[128 * 64];
    f32x4 acc[4][4];
    const int bx = blockIdx.x, by = blockIdx.y;
    gemm_main(A + (size_t)by * 128 * 4096, Bt + (size_t)bx * 128 * 4096, As, Bs, acc);

    const int tid = threadIdx.x, lane = tid & 63, w = tid >> 6;
    const int wm = (w >> 1) * 64, wn = (w & 1) * 64, l15 = lane & 15, l4 = lane >> 4;
#pragma unroll
    for (int m = 0; m < 4; ++m) {
        const int row = by * 128 + wm + m * 16 + l4 * 4;
#pragma unroll
        for (int n = 0; n < 4; ++n) {
            const int col = bx * 128 + wn + n * 16 + l15;
#pragma unroll
            for (int r = 0; r < 4; ++r) out[(size_t)(row + r) * DD + col] = acc[m][n][r];
        }
    }
}

// ---------------- launcher ----------------
extern "C" void kernel_launch(void* const* d_in, const int* in_sizes, int n_in,
                              void* d_out, int out_size, void* d_ws, size_t ws_size,
                              hipStream_t stream) {
    const float* x    = (const float*)d_in[0];
    const float* fc   = (const float*)d_in[1];
    const float* wqkv = (const float*)d_in[2];
    const float* wo   = (const float*)d_in[3];

    char* wsp = (char*)d_ws;
    const size_t MB = (size_t)1 << 20;
    bf16* xb    = (bf16*)(wsp);              // 32MB
    bf16* wqkvT = (bf16*)(wsp + 32 * MB);    // 48MB
    bf16* woT   = (bf16*)(wsp + 32 * MB);    // 32MB (aliases wqkvT; written after gemm_qkv)
    bf16* Qb    = (bf16*)(wsp + 80 * MB);    // 32MB
    bf16* Kb    = (bf16*)(wsp + 112 * MB);   //  8MB
    bf16* VTb   = (bf16*)(wsp + 120 * MB);   //  8MB
    bf16* Ab    = (bf16*)(wsp);              // attn out bf16 (aliases xb)
    float* out  = (float*)d_out;

    k_cvt_x<<<8192, 256, 0, stream>>>(x, xb);
    k_tr_cvt<<<dim3(NQKV / 64, DD / 64), 256, 0, stream>>>(wqkv, wqkvT, DD, NQKV);
    k_gemm_qkv<<<dim3(NQKV / 128, (BB * SS) / 128), 256, 0, stream>>>(xb, wqkvT, fc, Qb, Kb, VTb);
    k_tr_cvt<<<dim3(DD / 64, QDIM / 64), 256, 0, stream>>>(wo, woT, QDIM, DD);
    k_attn<<<dim3(8, NH, BB), 256, 0, stream>>>(Qb, Kb, VTb, Ab);
    k_gemm_out<<<dim3(DD / 128, (BB * SS) / 128), 256, 0, stream>>>(Ab, woT, out);
}

// Round 3
// 608.773 us; speedup vs baseline: 1.3133x; 1.0883x over previous
//
#include <hip/hip_runtime.h>
#include <stdint.h>
#include <stddef.h>

// ---------------- problem constants ----------------
#define BB 2
#define SS 2048
#define DD 4096
#define NH 32
#define NKV 8
#define HD 128
#define QDIM 4096
#define KVDIM 1024
#define NQKV 6144
#define NTILES 64  // K / 64
// 1/sqrt(128) * log2(e): Q pre-scale so softmax exp is a single v_exp_f32 (2^x)
#define QK_SCALE_L2E 0.12751744f

typedef __bf16 bf16;
typedef __bf16 bf16x8 __attribute__((ext_vector_type(8)));
typedef __bf16 bf16x4 __attribute__((ext_vector_type(4)));
typedef float f32x4 __attribute__((ext_vector_type(4)));

#define MFMA16(a, b, c) __builtin_amdgcn_mfma_f32_16x16x32_bf16((a), (b), (c), 0, 0, 0)
#define BAR() __builtin_amdgcn_s_barrier()
#define VMW10() asm volatile("s_waitcnt vmcnt(10)" ::: "memory")

typedef __attribute__((address_space(1))) void GASV;
typedef __attribute__((address_space(3))) void LASV;

__device__ __forceinline__ void gload_lds16(const void* g, void* l) {
    __builtin_amdgcn_global_load_lds((GASV*)g, (LASV*)l, 16, 0, 0);
}

__device__ __forceinline__ float fexp2(float x) {
    float r;
    asm("v_exp_f32 %0, %1" : "=v"(r) : "v"(x));
    return r;
}

// ---------------- fp32 -> bf16 convert (x) ----------------
__global__ __launch_bounds__(256) void k_cvt_x(const float* __restrict__ in,
                                               bf16* __restrict__ out) {
    size_t i = ((size_t)blockIdx.x * 256 + threadIdx.x) * 8;
    const float4 a = *(const float4*)(in + i);
    const float4 b = *(const float4*)(in + i + 4);
    bf16x8 v;
    v[0] = (bf16)a.x; v[1] = (bf16)a.y; v[2] = (bf16)a.z; v[3] = (bf16)a.w;
    v[4] = (bf16)b.x; v[5] = (bf16)b.y; v[6] = (bf16)b.z; v[7] = (bf16)b.w;
    *(bf16x8*)(out + i) = v;
}

// ---------------- transpose + convert: in[R][C] f32 -> out[C][R] bf16 ----------------
__global__ __launch_bounds__(256) void k_tr_cvt(const float* __restrict__ in,
                                                bf16* __restrict__ out, int R, int C) {
    __shared__ float tile[64][65];
    const int t = threadIdx.x;
    const int tx = t & 15, ty = t >> 4;
    const int r0 = blockIdx.y * 64, c0 = blockIdx.x * 64;
#pragma unroll
    for (int p = 0; p < 4; ++p) {
        const float4 v = *(const float4*)(in + (size_t)(r0 + p * 16 + ty) * C + c0 + tx * 4);
        tile[p * 16 + ty][tx * 4 + 0] = v.x;
        tile[p * 16 + ty][tx * 4 + 1] = v.y;
        tile[p * 16 + ty][tx * 4 + 2] = v.z;
        tile[p * 16 + ty][tx * 4 + 3] = v.w;
    }
    __syncthreads();
#pragma unroll
    for (int p = 0; p < 4; ++p) {
        const int oc = c0 + p * 16 + ty;
        bf16x4 pk;
#pragma unroll
        for (int j = 0; j < 4; ++j) pk[j] = (bf16)tile[tx * 4 + j][p * 16 + ty];
        *(bf16x4*)(out + (size_t)oc * R + r0 + tx * 4) = pk;
    }
}

// ================= 256x256 8-phase GEMM core =================
// 512 thr / 8 waves (2M x 4N). Per-wave C: rows {wm*64..+63} U {128+wm*64..+63},
// cols {wn*32..+31} U {128+wn*32..+31} -> each phase = one A-half x one B-half,
// 16 MFMA. ds_reads run one phase ahead of use; 1 half-tile (2 gload_lds/thread)
// staged per phase, rotation [A0,B0,B1,A1]; every read target has exactly 10
// younger loads at its protecting vmcnt -> uniform vmcnt(10), never a drain in
// the main loop. LDS 128KB: A/B each [2 dbuf][2 half][128 rows][64 k] bf16,
// XOR-8 chunk swizzle (phys chunk = cc ^ (row&7)) applied on the pre-swizzled
// global source (write side) and on ds_read (read side).

__device__ __forceinline__ void stage_half(char* ldsRegion, const bf16* gsrc) {
    const int t = threadIdx.x;
    const int wid = t >> 6;
#pragma unroll
    for (int i = 0; i < 2; ++i) {
        const int off = i * 8192 + t * 16;
        const int row = off >> 7;          // row within half (128B rows)
        const int pc = (off >> 4) & 7;     // phys chunk
        const int lc = pc ^ (row & 7);     // logical chunk fetched into phys slot
        gload_lds16(gsrc + (size_t)row * 4096 + lc * 8,
                    ldsRegion + i * 8192 + wid * 1024);
    }
}

__device__ __forceinline__ void gemm256(const bf16* __restrict__ At,
                                        const bf16* __restrict__ Bt,
                                        char* LB, f32x4 acc[8][4]) {
    const int tid = threadIdx.x, lane = tid & 63, wid = tid >> 6;
    const int wm = wid >> 2, wn = wid & 3;
    const int l15 = lane & 15, l4 = lane >> 4;

    const f32x4 vz = {0.f, 0.f, 0.f, 0.f};
#pragma unroll
    for (int m = 0; m < 8; ++m)
#pragma unroll
        for (int n = 0; n < 4; ++n) acc[m][n] = vz;

    auto Areg = [&](int db, int h) -> char* { return LB + db * 32768 + h * 16384; };
    auto Breg = [&](int db, int h) -> char* { return LB + 65536 + db * 32768 + h * 16384; };

    bf16x8 Aa[2][4], Ab[2][4], B0r[2][2], B1r[2][2];

    auto loadA = [&](bf16x8 dst[2][4], int db, int h) {
        char* base = Areg(db, h);
#pragma unroll
        for (int kk = 0; kk < 2; ++kk)
#pragma unroll
            for (int mf = 0; mf < 4; ++mf) {
                const int row = wm * 64 + mf * 16 + l15;
                const int cc = kk * 4 + l4;
                dst[kk][mf] = *(const bf16x8*)(base + row * 128 + ((cc ^ (row & 7)) << 4));
            }
    };
    auto loadB = [&](bf16x8 dst[2][2], int db, int h) {
        char* base = Breg(db, h);
#pragma unroll
        for (int kk = 0; kk < 2; ++kk)
#pragma unroll
            for (int nf = 0; nf < 2; ++nf) {
                const int row = wn * 32 + nf * 16 + l15;
                const int cc = kk * 4 + l4;
                dst[kk][nf] = *(const bf16x8*)(base + row * 128 + ((cc ^ (row & 7)) << 4));
            }
    };
    auto stA = [&](int tau, int h) {
        stage_half(Areg(tau & 1, h), At + (size_t)(h * 128) * 4096 + tau * 64);
    };
    auto stB = [&](int tau, int h) {
        stage_half(Breg(tau & 1, h), Bt + (size_t)(h * 128) * 4096 + tau * 64);
    };
    auto mma = [&](bf16x8 A[2][4], bf16x8 B[2][2], int mb, int nb) {
        __builtin_amdgcn_s_setprio(1);
#pragma unroll
        for (int kk = 0; kk < 2; ++kk)
#pragma unroll
            for (int mf = 0; mf < 4; ++mf)
#pragma unroll
                for (int nf = 0; nf < 2; ++nf)
                    acc[mb + mf][nb + nf] = MFMA16(A[kk][mf], B[kk][nf], acc[mb + mf][nb + nf]);
        __builtin_amdgcn_s_setprio(0);
    };

    // ---- prologue: stage tiles 0,1 (16 loads/thread), wait tile0, read its A0/B0
    stA(0, 0); stB(0, 0); stB(0, 1); stA(0, 1);
    stA(1, 0); stB(1, 0); stB(1, 1); stA(1, 1);
    asm volatile("s_waitcnt vmcnt(8)" ::: "memory");
    BAR();
    loadA(Aa, 0, 0);
    loadB(B0r, 0, 0);

    // ---- main loop: tiles 0..61 full-rate
#pragma unroll 1
    for (int tau = 0; tau < NTILES - 2; ++tau) {
        const int db = tau & 1, ndb = db ^ 1;
        // p1: read tau.B1 ; stage (tau+2).A0 ; MFMA (A0,B0)
        loadB(B1r, db, 1);
        stA(tau + 2, 0);
        VMW10(); BAR();
        mma(Aa, B0r, 0, 0);
        BAR();
        // p2: read tau.A1 ; stage (tau+2).B0 ; MFMA (A0,B1)
        loadA(Ab, db, 1);
        stB(tau + 2, 0);
        VMW10(); BAR();
        mma(Aa, B1r, 0, 2);
        BAR();
        // p3: stage (tau+2).B1 ; MFMA (A1,B0)
        stB(tau + 2, 1);
        VMW10(); BAR();
        mma(Ab, B0r, 4, 0);
        BAR();
        // p4: read (tau+1).A0/B0 ; stage (tau+2).A1 ; MFMA (A1,B1)
        loadA(Aa, ndb, 0);
        loadB(B0r, ndb, 0);
        stA(tau + 2, 1);
        VMW10(); BAR();
        mma(Ab, B1r, 4, 2);
        BAR();
    }

    // ---- tail: tiles 62,63 — everything already staged; full drain once
    asm volatile("s_waitcnt vmcnt(0)" ::: "memory");
    BAR();
#pragma unroll 1
    for (int tau = NTILES - 2; tau < NTILES; ++tau) {
        const int db = tau & 1, ndb = db ^ 1;
        loadB(B1r, db, 1);
        BAR(); mma(Aa, B0r, 0, 0); BAR();
        loadA(Ab, db, 1);
        BAR(); mma(Aa, B1r, 0, 2); BAR();
        BAR(); mma(Ab, B0r, 4, 0); BAR();
        if (tau < NTILES - 1) { loadA(Aa, ndb, 0); loadB(B0r, ndb, 0); }
        BAR(); mma(Ab, B1r, 4, 2); BAR();
    }
}

// ---------------- GEMM 1: xqkv = x @ wqkv, fused RoPE, writes Q,K,V^T ----------------
__global__ __launch_bounds__(512, 2) void k_gemm_qkv(const bf16* __restrict__ A,
                                                     const bf16* __restrict__ Bt,
                                                     const float* __restrict__ fc,
                                                     bf16* __restrict__ Qb,
                                                     bf16* __restrict__ Kb,
                                                     bf16* __restrict__ VTb) {
    __shared__ __align__(16) char LB[131072];
    f32x4 acc[8][4];
    const int bx = blockIdx.x, by = blockIdx.y;
    gemm256(A + (size_t)by * 256 * 4096, Bt + (size_t)bx * 256 * 4096, LB, acc);

    const int tid = threadIdx.x, lane = tid & 63, wid = tid >> 6;
    const int wm = wid >> 2, wn = wid & 3;
    const int l15 = lane & 15, l4 = lane >> 4;
    const int n0r = bx * 256;  // block-uniform region selector (regions 1024-aligned)
#pragma unroll
    for (int mf = 0; mf < 8; ++mf) {
        const int rowbase = by * 256 + (mf >> 2) * 128 + wm * 64 + (mf & 3) * 16 + l4 * 4;
#pragma unroll
        for (int nf = 0; nf < 4; ++nf) {
            const int col = n0r + (nf >> 1) * 128 + wn * 32 + (nf & 1) * 16 + l15;
            f32x4 v = acc[mf][nf];
            if (n0r < QDIM + KVDIM) {
                // Q or K: RoPE. Paired column col^1 lives in lane^1 (C-layout col=lane&15).
                const int d = col & (HD - 1);
                const int dp = d & ~1;
                const float sgn = (d & 1) ? 1.f : -1.f;
#pragma unroll
                for (int r = 0; r < 4; ++r) {
                    const int row = rowbase + r;
                    const int s = row & (SS - 1);
                    const float2 sc = *(const float2*)(fc + s * HD + dp);  // (sin, cos)
                    const float partner = __shfl_xor(v[r], 1);
                    float res = v[r] * sc.y + sgn * partner * sc.x;
                    if (n0r < QDIM) {
                        res *= QK_SCALE_L2E;
                        Qb[(size_t)row * QDIM + col] = (bf16)res;
                    } else {
                        Kb[(size_t)row * KVDIM + (col - QDIM)] = (bf16)res;
                    }
                }
            } else {
                // V: write transposed [b][kvh][d][s]; 4 consecutive s -> 8B store
                const int hdv = col - (QDIM + KVDIM);
                const int kvh = hdv >> 7, dd = hdv & (HD - 1);
                const int bb = rowbase >> 11, s = rowbase & (SS - 1);
                bf16x4 pk;
#pragma unroll
                for (int r = 0; r < 4; ++r) pk[r] = (bf16)v[r];
                *(bf16x4*)(VTb + ((size_t)((bb * NKV + kvh) * HD + dd)) * SS + s) = pk;
            }
        }
    }
}

// ---------------- GEMM 2: out = attn @ wo (f32 output) ----------------
__global__ __launch_bounds__(512, 2) void k_gemm_out(const bf16* __restrict__ A,
                                                     const bf16* __restrict__ Bt,
                                                     float* __restrict__ out) {
    __shared__ __align__(16) char LB[131072];
    f32x4 acc[8][4];
    const int bx = blockIdx.x, by = blockIdx.y;
    gemm256(A + (size_t)by * 256 * 4096, Bt + (size_t)bx * 256 * 4096, LB, acc);

    const int tid = threadIdx.x, lane = tid & 63, wid = tid >> 6;
    const int wm = wid >> 2, wn = wid & 3;
    const int l15 = lane & 15, l4 = lane >> 4;
#pragma unroll
    for (int mf = 0; mf < 8; ++mf) {
        const int row = by * 256 + (mf >> 2) * 128 + wm * 64 + (mf & 3) * 16 + l4 * 4;
#pragma unroll
        for (int nf = 0; nf < 4; ++nf) {
            const int col = bx * 256 + (nf >> 1) * 128 + wn * 32 + (nf & 1) * 16 + l15;
#pragma unroll
            for (int r = 0; r < 4; ++r) out[(size_t)(row + r) * DD + col] = acc[mf][nf][r];
        }
    }
}

// ---------------- flash attention (r2 structure, unchanged) ----------------
__global__ __launch_bounds__(256, 2) void k_attn(const bf16* __restrict__ Qb,
                                                 const bf16* __restrict__ Kb,
                                                 const bf16* __restrict__ VTb,
                                                 bf16* __restrict__ Ob) {
    __shared__ __align__(16) bf16 Ks[64 * 128];
    __shared__ __align__(16) bf16 Vs[128 * 64];
    __shared__ __align__(16) bf16 Ps[4][32 * 88];
    const int jj = blockIdx.x, h = blockIdx.y, b = blockIdx.z;
    const int kvh = h >> 2;
    const int tid = threadIdx.x, lane = tid & 63, w = tid >> 6;
    const int l15 = lane & 15, l4 = lane >> 4;

    const bf16* Kg = Kb + (size_t)b * SS * KVDIM + kvh * HD;
    const bf16* Vg = VTb + (size_t)(b * NKV + kvh) * HD * SS;

    int4 kreg[4], vreg[4];
    const f32x4 vz = {0.f, 0.f, 0.f, 0.f};

    auto issue_kv = [&](int t) {
#pragma unroll
        for (int i = 0; i < 4; ++i) {
            const int off = i * 4096 + tid * 16;
            const int row = off >> 8;
            const int cc = (off >> 4) & 15;
            kreg[i] = *(const int4*)((const char*)(Kg + (size_t)(t * 64 + row) * KVDIM) + cc * 16);
        }
#pragma unroll
        for (int i = 0; i < 4; ++i) {
            const int off = i * 4096 + tid * 16;
            const int row = off >> 7;
            const int cc = (off >> 4) & 7;
            vreg[i] = *(const int4*)((const char*)(Vg + (size_t)row * SS + t * 64) + cc * 16);
        }
    };

#pragma unroll 1
    for (int pj = 0; pj < 2; ++pj) {
        const int j = pj ? (15 - jj) : jj;
        const int q0 = j * 128;
        const int nt = 2 * j + 2;

        bf16x8 qf[2][4];
#pragma unroll
        for (int m = 0; m < 2; ++m) {
            const int qrow = q0 + w * 32 + m * 16 + l15;
            const bf16* qb = Qb + ((size_t)(b * SS + qrow) << 12) + h * HD + l4 * 8;
#pragma unroll
            for (int kc = 0; kc < 4; ++kc) qf[m][kc] = *(const bf16x8*)(qb + kc * 32);
        }

        f32x4 o[2][8];
#pragma unroll
        for (int m = 0; m < 2; ++m)
#pragma unroll
            for (int df = 0; df < 8; ++df) o[m][df] = vz;
        float m_run[2][4], l_run[2][4];
#pragma unroll
        for (int m = 0; m < 2; ++m)
#pragma unroll
            for (int r = 0; r < 4; ++r) { m_run[m][r] = -1e30f; l_run[m][r] = 0.f; }

        issue_kv(0);

        for (int t = 0; t < nt; ++t) {
            __syncthreads();
#pragma unroll
            for (int i = 0; i < 4; ++i) {
                const int off = i * 4096 + tid * 16;
                const int row = off >> 8;
                const int cc = (off >> 4) & 15;
                const int lc = cc ^ (row & 7);
                *(int4*)((char*)Ks + row * 256 + lc * 16) = kreg[i];
            }
#pragma unroll
            for (int i = 0; i < 4; ++i) {
                const int off = i * 4096 + tid * 16;
                const int row = off >> 7;
                const int cc = (off >> 4) & 7;
                const int lc = cc ^ (row & 7);
                *(int4*)((char*)Vs + row * 128 + lc * 16) = vreg[i];
            }
            __syncthreads();

            if (t + 1 < nt) issue_kv(t + 1);

            f32x4 sa[2][4];
#pragma unroll
            for (int m = 0; m < 2; ++m)
#pragma unroll
                for (int n = 0; n < 4; ++n) sa[m][n] = vz;
            __builtin_amdgcn_s_setprio(1);
#pragma unroll
            for (int kc = 0; kc < 4; ++kc)
#pragma unroll
                for (int n = 0; n < 4; ++n) {
                    const int krow = n * 16 + l15;
                    const int cc = kc * 4 + l4;
                    const bf16x8 kf =
                        *(const bf16x8*)((const char*)Ks + (krow << 8) + ((cc ^ (krow & 7)) << 4));
                    sa[0][n] = MFMA16(qf[0][kc], kf, sa[0][n]);
                    sa[1][n] = MFMA16(qf[1][kc], kf, sa[1][n]);
                }
            __builtin_amdgcn_s_setprio(0);

            if (t >= 2 * j) {
#pragma unroll
                for (int m = 0; m < 2; ++m)
#pragma unroll
                    for (int n = 0; n < 4; ++n)
#pragma unroll
                        for (int r = 0; r < 4; ++r) {
                            const int col = t * 64 + n * 16 + l15;
                            const int qr = q0 + w * 32 + m * 16 + l4 * 4 + r;
                            if (col > qr) sa[m][n][r] = -1e30f;
                        }
            }

#pragma unroll
            for (int m = 0; m < 2; ++m)
#pragma unroll
                for (int r = 0; r < 4; ++r) {
                    float mx = fmaxf(fmaxf(sa[m][0][r], sa[m][1][r]),
                                     fmaxf(sa[m][2][r], sa[m][3][r]));
#pragma unroll
                    for (int mk = 1; mk <= 8; mk <<= 1) mx = fmaxf(mx, __shfl_xor(mx, mk));
                    const float mn = fmaxf(m_run[m][r], mx);
                    const float alpha = fexp2(m_run[m][r] - mn);
                    m_run[m][r] = mn;
                    float rs = 0.f;
#pragma unroll
                    for (int n = 0; n < 4; ++n) {
                        const float p = fexp2(sa[m][n][r] - mn);
                        sa[m][n][r] = p;
                        rs += p;
                    }
#pragma unroll
                    for (int mk = 1; mk <= 8; mk <<= 1) rs += __shfl_xor(rs, mk);
                    l_run[m][r] = l_run[m][r] * alpha + rs;
#pragma unroll
                    for (int df = 0; df < 8; ++df) o[m][df][r] *= alpha;
                }

#pragma unroll
            for (int m = 0; m < 2; ++m)
#pragma unroll
                for (int n = 0; n < 4; ++n)
#pragma unroll
                    for (int r = 0; r < 4; ++r)
                        Ps[w][(m * 16 + l4 * 4 + r) * 88 + n * 16 + l15] = (bf16)sa[m][n][r];

            bf16x8 pf0[2], pf1[2];
#pragma unroll
            for (int ks = 0; ks < 2; ++ks) {
                pf0[ks] = *(const bf16x8*)(&Ps[w][l15 * 88 + ks * 32 + l4 * 8]);
                pf1[ks] = *(const bf16x8*)(&Ps[w][(16 + l15) * 88 + ks * 32 + l4 * 8]);
            }

            __builtin_amdgcn_s_setprio(1);
#pragma unroll
            for (int df = 0; df < 8; ++df)
#pragma unroll
                for (int ks = 0; ks < 2; ++ks) {
                    const int vrow = df * 16 + l15;
                    const int cc = ks * 4 + l4;
                    const bf16x8 vf =
                        *(const bf16x8*)((const char*)Vs + (vrow << 7) + ((cc ^ (vrow & 7)) << 4));
                    o[0][df] = MFMA16(pf0[ks], vf, o[0][df]);
                    o[1][df] = MFMA16(pf1[ks], vf, o[1][df]);
                }
            __builtin_amdgcn_s_setprio(0);
        }

#pragma unroll
        for (int m = 0; m < 2; ++m)
#pragma unroll
            for (int r = 0; r < 4; ++r) {
                const float inv = 1.f / l_run[m][r];
                const size_t row = (size_t)(b * SS + q0 + w * 32 + m * 16 + l4 * 4 + r);
#pragma unroll
                for (int df = 0; df < 8; ++df)
                    Ob[(row << 12) + h * HD + df * 16 + l15] = (bf16)(o[m][df][r] * inv);
            }
    }
}

// ---------------- launcher ----------------
extern "C" void kernel_launch(void* const* d_in, const int* in_sizes, int n_in,
                              void* d_out, int out_size, void* d_ws, size_t ws_size,
                              hipStream_t stream) {
    const float* x    = (const float*)d_in[0];
    const float* fc   = (const float*)d_in[1];
    const float* wqkv = (const float*)d_in[2];
    const float* wo   = (const float*)d_in[3];

    char* wsp = (char*)d_ws;
    const size_t MB = (size_t)1 << 20;
    bf16* xb    = (bf16*)(wsp);              // 32MB
    bf16* wqkvT = (bf16*)(wsp + 32 * MB);    // 48MB
    bf16* woT   = (bf16*)(wsp + 32 * MB);    // 32MB (aliases wqkvT; written after gemm_qkv)
    bf16* Qb    = (bf16*)(wsp + 80 * MB);    // 32MB
    bf16* Kb    = (bf16*)(wsp + 112 * MB);   //  8MB
    bf16* VTb   = (bf16*)(wsp + 120 * MB);   //  8MB
    bf16* Ab    = (bf16*)(wsp);              // attn out bf16 (aliases xb)
    float* out  = (float*)d_out;

    k_cvt_x<<<8192, 256, 0, stream>>>(x, xb);
    k_tr_cvt<<<dim3(NQKV / 64, DD / 64), 256, 0, stream>>>(wqkv, wqkvT, DD, NQKV);
    k_gemm_qkv<<<dim3(NQKV / 256, (BB * SS) / 256), 512, 0, stream>>>(xb, wqkvT, fc, Qb, Kb, VTb);
    k_tr_cvt<<<dim3(DD / 64, QDIM / 64), 256, 0, stream>>>(wo, woT, QDIM, DD);
    k_attn<<<dim3(8, NH, BB), 256, 0, stream>>>(Qb, Kb, VTb, Ab);
    k_gemm_out<<<dim3(DD / 256, (BB * SS) / 256), 512, 0, stream>>>(Ab, woT, out);
}

// Round 5
// 605.304 us; speedup vs baseline: 1.3208x; 1.0057x over previous
//
#include <hip/hip_runtime.h>
#include <stdint.h>
#include <stddef.h>

// ---------------- problem constants ----------------
#define BB 2
#define SS 2048
#define DD 4096
#define NH 32
#define NKV 8
#define HD 128
#define QDIM 4096
#define KVDIM 1024
#define NQKV 6144
#define NTILES 64  // K / 64
// 1/sqrt(128) * log2(e): Q pre-scale so softmax exp is a single v_exp_f32 (2^x)
#define QK_SCALE_L2E 0.12751744f

typedef __bf16 bf16;
typedef __bf16 bf16x8 __attribute__((ext_vector_type(8)));
typedef __bf16 bf16x4 __attribute__((ext_vector_type(4)));
typedef float f32x4 __attribute__((ext_vector_type(4)));

#define MFMA16(a, b, c) __builtin_amdgcn_mfma_f32_16x16x32_bf16((a), (b), (c), 0, 0, 0)
#define BAR() __builtin_amdgcn_s_barrier()
#define VMW10() asm volatile("s_waitcnt vmcnt(10)" ::: "memory")
#define VMW8() asm volatile("s_waitcnt vmcnt(8)" ::: "memory")

typedef __attribute__((address_space(1))) void GASV;
typedef __attribute__((address_space(3))) void LASV;

__device__ __forceinline__ void gload_lds16(const void* g, void* l) {
    __builtin_amdgcn_global_load_lds((GASV*)g, (LASV*)l, 16, 0, 0);
}

__device__ __forceinline__ float fexp2(float x) {
    float r;
    asm("v_exp_f32 %0, %1" : "=v"(r) : "v"(x));
    return r;
}

// ---------------- fp32 -> bf16 convert (x) ----------------
__global__ __launch_bounds__(256) void k_cvt_x(const float* __restrict__ in,
                                               bf16* __restrict__ out) {
    size_t i = ((size_t)blockIdx.x * 256 + threadIdx.x) * 8;
    const float4 a = *(const float4*)(in + i);
    const float4 b = *(const float4*)(in + i + 4);
    bf16x8 v;
    v[0] = (bf16)a.x; v[1] = (bf16)a.y; v[2] = (bf16)a.z; v[3] = (bf16)a.w;
    v[4] = (bf16)b.x; v[5] = (bf16)b.y; v[6] = (bf16)b.z; v[7] = (bf16)b.w;
    *(bf16x8*)(out + i) = v;
}

// ---------------- transpose + convert: in[R][C] f32 -> out[C][R] bf16 ----------------
__global__ __launch_bounds__(256) void k_tr_cvt(const float* __restrict__ in,
                                                bf16* __restrict__ out, int R, int C) {
    __shared__ float tile[64][65];
    const int t = threadIdx.x;
    const int tx = t & 15, ty = t >> 4;
    const int r0 = blockIdx.y * 64, c0 = blockIdx.x * 64;
#pragma unroll
    for (int p = 0; p < 4; ++p) {
        const float4 v = *(const float4*)(in + (size_t)(r0 + p * 16 + ty) * C + c0 + tx * 4);
        tile[p * 16 + ty][tx * 4 + 0] = v.x;
        tile[p * 16 + ty][tx * 4 + 1] = v.y;
        tile[p * 16 + ty][tx * 4 + 2] = v.z;
        tile[p * 16 + ty][tx * 4 + 3] = v.w;
    }
    __syncthreads();
#pragma unroll
    for (int p = 0; p < 4; ++p) {
        const int oc = c0 + p * 16 + ty;
        bf16x4 pk;
#pragma unroll
        for (int j = 0; j < 4; ++j) pk[j] = (bf16)tile[tx * 4 + j][p * 16 + ty];
        *(bf16x4*)(out + (size_t)oc * R + r0 + tx * 4) = pk;
    }
}

// ================= 256x256 8-phase GEMM core (r5: r3 dataflow + counted vmcnt) =====
// 512 thr / 8 waves (2M x 4N). Read placement is r3's (validated): p1 reads B1(tau),
// p2 reads A1(tau), p4 reads A0/B0(tau+1) -- no register is overwritten before its
// last consuming MFMA (the r4 bug). Waits: vmcnt(10) at p3 (10 loads younger than
// stB(tau+1,0) => covers p4's A0/B0 reads), vmcnt(8) at p4 (8 younger than
// stA(tau+1,1) => covers next p1/p2's B1/A1 reads). p1/p2: no vmem wait. Counted,
// never drained in the main loop (T4). XOR-8 chunk swizzle both sides.

__device__ __forceinline__ void stage_half(char* ldsRegion, const bf16* gsrc) {
    const int t = threadIdx.x;
    const int wid = t >> 6;
#pragma unroll
    for (int i = 0; i < 2; ++i) {
        const int off = i * 8192 + t * 16;
        const int row = off >> 7;          // row within half (128B rows)
        const int pc = (off >> 4) & 7;     // phys chunk
        const int lc = pc ^ (row & 7);     // logical chunk fetched into phys slot
        gload_lds16(gsrc + (size_t)row * 4096 + lc * 8,
                    ldsRegion + i * 8192 + wid * 1024);
    }
}

__device__ __forceinline__ void gemm256(const bf16* __restrict__ At,
                                        const bf16* __restrict__ Bt,
                                        char* LB, f32x4 acc[8][4]) {
    const int tid = threadIdx.x, lane = tid & 63, wid = tid >> 6;
    const int wm = wid >> 2, wn = wid & 3;
    const int l15 = lane & 15, l4 = lane >> 4;

    const f32x4 vz = {0.f, 0.f, 0.f, 0.f};
#pragma unroll
    for (int m = 0; m < 8; ++m)
#pragma unroll
        for (int n = 0; n < 4; ++n) acc[m][n] = vz;

    auto Areg = [&](int db, int h) -> char* { return LB + db * 32768 + h * 16384; };
    auto Breg = [&](int db, int h) -> char* { return LB + 65536 + db * 32768 + h * 16384; };

    bf16x8 RA[2][4], RAb[2][4], RB0[2][2], RB1[2][2];

    auto loadA = [&](bf16x8 dst[2][4], int db, int h) {
        char* base = Areg(db, h);
#pragma unroll
        for (int kk = 0; kk < 2; ++kk)
#pragma unroll
            for (int mf = 0; mf < 4; ++mf) {
                const int row = wm * 64 + mf * 16 + l15;
                const int cc = kk * 4 + l4;
                dst[kk][mf] = *(const bf16x8*)(base + row * 128 + ((cc ^ (row & 7)) << 4));
            }
    };
    auto loadB = [&](bf16x8 dst[2][2], int db, int h) {
        char* base = Breg(db, h);
#pragma unroll
        for (int kk = 0; kk < 2; ++kk)
#pragma unroll
            for (int nf = 0; nf < 2; ++nf) {
                const int row = wn * 32 + nf * 16 + l15;
                const int cc = kk * 4 + l4;
                dst[kk][nf] = *(const bf16x8*)(base + row * 128 + ((cc ^ (row & 7)) << 4));
            }
    };
    auto stA = [&](int tau, int h) {
        stage_half(Areg(tau & 1, h), At + (size_t)(h * 128) * 4096 + tau * 64);
    };
    auto stB = [&](int tau, int h) {
        stage_half(Breg(tau & 1, h), Bt + (size_t)(h * 128) * 4096 + tau * 64);
    };
    auto mma = [&](bf16x8 A[2][4], bf16x8 B[2][2], int mb, int nb) {
        __builtin_amdgcn_s_setprio(1);
#pragma unroll
        for (int kk = 0; kk < 2; ++kk)
#pragma unroll
            for (int mf = 0; mf < 4; ++mf)
#pragma unroll
                for (int nf = 0; nf < 2; ++nf)
                    acc[mb + mf][nb + nf] = MFMA16(A[kk][mf], B[kk][nf], acc[mb + mf][nb + nf]);
        __builtin_amdgcn_s_setprio(0);
    };

    // ---- prologue: stage tiles 0,1 (16 loads/thread); vmcnt(8) => tile0 landed
    stA(0, 0); stB(0, 0); stB(0, 1); stA(0, 1);
    stA(1, 0); stB(1, 0); stB(1, 1); stA(1, 1);
    VMW8();
    BAR();
    loadA(RA, 0, 0); loadB(RB0, 0, 0);

    // ---- main loop: tiles 0..61; stages tiles 2..63
#pragma unroll 1
    for (int tau = 0; tau < NTILES - 2; ++tau) {
        const int db = tau & 1, ndb = db ^ 1;
        // p1: read tau.B1 ; stage (tau+2).A0 ; MFMA (A0,B0)
        loadB(RB1, db, 1);
        stA(tau + 2, 0);
        BAR();
        mma(RA, RB0, 0, 0);
        BAR();
        // p2: read tau.A1 ; stage (tau+2).B0 ; MFMA (A0,B1)
        loadA(RAb, db, 1);
        stB(tau + 2, 0);
        BAR();
        mma(RA, RB1, 0, 2);
        BAR();
        // p3: stage (tau+2).B1 ; vmcnt(10) ; MFMA (A1,B0)
        stB(tau + 2, 1);
        VMW10();
        BAR();
        mma(RAb, RB0, 4, 0);
        BAR();
        // p4: read (tau+1).{A0,B0} ; stage (tau+2).A1 ; vmcnt(8) ; MFMA (A1,B1)
        loadA(RA, ndb, 0);
        loadB(RB0, ndb, 0);
        stA(tau + 2, 1);
        VMW8();
        BAR();
        mma(RAb, RB1, 4, 2);
        BAR();
    }

    // ---- tail: tiles 62,63 fully staged; one drain, then barrier-free compute
    asm volatile("s_waitcnt vmcnt(0)" ::: "memory");
    BAR();
#pragma unroll 1
    for (int tau = NTILES - 2; tau < NTILES; ++tau) {
        const int db = tau & 1, ndb = db ^ 1;
        loadB(RB1, db, 1);          // RB1 free: last used at previous tile's final mma
        mma(RA, RB0, 0, 0);
        loadA(RAb, db, 1);
        mma(RA, RB1, 0, 2);
        mma(RAb, RB0, 4, 0);
        if (tau < NTILES - 1) { loadA(RA, ndb, 0); loadB(RB0, ndb, 0); }
        mma(RAb, RB1, 4, 2);
    }
}

// bijective XCD-chunk swizzle (nwg % 8 == 0 for all our grids)
__device__ __forceinline__ void xcd_swizzle(int gx, int& bx, int& by) {
    const int nwg = gx * gridDim.y;
    int lin = by * gx + bx;
    lin = (lin & 7) * (nwg >> 3) + (lin >> 3);
    bx = lin % gx;
    by = lin / gx;
}

// ---------------- GEMM 1: xqkv = x @ wqkv, fused RoPE, writes Q,K,V^T ----------------
__global__ __launch_bounds__(512, 2) void k_gemm_qkv(const bf16* __restrict__ A,
                                                     const bf16* __restrict__ Bt,
                                                     const float* __restrict__ fc,
                                                     bf16* __restrict__ Qb,
                                                     bf16* __restrict__ Kb,
                                                     bf16* __restrict__ VTb) {
    __shared__ __align__(16) char LB[131072];
    f32x4 acc[8][4];
    int bx = blockIdx.x, by = blockIdx.y;
    xcd_swizzle(NQKV / 256, bx, by);
    gemm256(A + (size_t)by * 256 * 4096, Bt + (size_t)bx * 256 * 4096, LB, acc);

    const int tid = threadIdx.x, lane = tid & 63, wid = tid >> 6;
    const int wm = wid >> 2, wn = wid & 3;
    const int l15 = lane & 15, l4 = lane >> 4;
    const int n0r = bx * 256;  // block-uniform region selector (regions 1024-aligned)
#pragma unroll
    for (int mf = 0; mf < 8; ++mf) {
        const int rowbase = by * 256 + (mf >> 2) * 128 + wm * 64 + (mf & 3) * 16 + l4 * 4;
#pragma unroll
        for (int nf = 0; nf < 4; ++nf) {
            const int col = n0r + (nf >> 1) * 128 + wn * 32 + (nf & 1) * 16 + l15;
            f32x4 v = acc[mf][nf];
            if (n0r < QDIM + KVDIM) {
                // Q or K: RoPE. Paired column col^1 lives in lane^1 (C-layout col=lane&15).
                const int d = col & (HD - 1);
                const int dp = d & ~1;
                const float sgn = (d & 1) ? 1.f : -1.f;
#pragma unroll
                for (int r = 0; r < 4; ++r) {
                    const int row = rowbase + r;
                    const int s = row & (SS - 1);
                    const float2 sc = *(const float2*)(fc + s * HD + dp);  // (sin, cos)
                    const float partner = __shfl_xor(v[r], 1);
                    float res = v[r] * sc.y + sgn * partner * sc.x;
                    if (n0r < QDIM) {
                        res *= QK_SCALE_L2E;
                        Qb[(size_t)row * QDIM + col] = (bf16)res;
                    } else {
                        Kb[(size_t)row * KVDIM + (col - QDIM)] = (bf16)res;
                    }
                }
            } else {
                // V: write transposed [b][kvh][d][s]; 4 consecutive s -> 8B store
                const int hdv = col - (QDIM + KVDIM);
                const int kvh = hdv >> 7, dd = hdv & (HD - 1);
                const int bb = rowbase >> 11, s = rowbase & (SS - 1);
                bf16x4 pk;
#pragma unroll
                for (int r = 0; r < 4; ++r) pk[r] = (bf16)v[r];
                *(bf16x4*)(VTb + ((size_t)((bb * NKV + kvh) * HD + dd)) * SS + s) = pk;
            }
        }
    }
}

// ---------------- GEMM 2: out = attn @ wo (f32 output) ----------------
__global__ __launch_bounds__(512, 2) void k_gemm_out(const bf16* __restrict__ A,
                                                     const bf16* __restrict__ Bt,
                                                     float* __restrict__ out) {
    __shared__ __align__(16) char LB[131072];
    f32x4 acc[8][4];
    int bx = blockIdx.x, by = blockIdx.y;
    xcd_swizzle(DD / 256, bx, by);
    gemm256(A + (size_t)by * 256 * 4096, Bt + (size_t)bx * 256 * 4096, LB, acc);

    const int tid = threadIdx.x, lane = tid & 63, wid = tid >> 6;
    const int wm = wid >> 2, wn = wid & 3;
    const int l15 = lane & 15, l4 = lane >> 4;
#pragma unroll
    for (int mf = 0; mf < 8; ++mf) {
        const int row = by * 256 + (mf >> 2) * 128 + wm * 64 + (mf & 3) * 16 + l4 * 4;
#pragma unroll
        for (int nf = 0; nf < 4; ++nf) {
            const int col = bx * 256 + (nf >> 1) * 128 + wn * 32 + (nf & 1) * 16 + l15;
#pragma unroll
            for (int r = 0; r < 4; ++r) out[(size_t)(row + r) * DD + col] = acc[mf][nf][r];
        }
    }
}

// ---------------- flash attention (r2 structure + XCD swizzle) ----------------
__global__ __launch_bounds__(256, 2) void k_attn(const bf16* __restrict__ Qb,
                                                 const bf16* __restrict__ Kb,
                                                 const bf16* __restrict__ VTb,
                                                 bf16* __restrict__ Ob) {
    __shared__ __align__(16) bf16 Ks[64 * 128];
    __shared__ __align__(16) bf16 Vs[128 * 64];
    __shared__ __align__(16) bf16 Ps[4][32 * 88];
    // swizzle 512 blocks -> 64 consecutive per XCD (2 kvh-groups' K/V L2-resident)
    int lin = (blockIdx.z * NH + blockIdx.y) * 8 + blockIdx.x;
    lin = (lin & 7) * 64 + (lin >> 3);
    const int jj = lin & 7, h = (lin >> 3) & (NH - 1), b = lin >> 8;
    const int kvh = h >> 2;
    const int tid = threadIdx.x, lane = tid & 63, w = tid >> 6;
    const int l15 = lane & 15, l4 = lane >> 4;

    const bf16* Kg = Kb + (size_t)b * SS * KVDIM + kvh * HD;
    const bf16* Vg = VTb + (size_t)(b * NKV + kvh) * HD * SS;

    int4 kreg[4], vreg[4];
    const f32x4 vz = {0.f, 0.f, 0.f, 0.f};

    auto issue_kv = [&](int t) {
#pragma unroll
        for (int i = 0; i < 4; ++i) {
            const int off = i * 4096 + tid * 16;
            const int row = off >> 8;
            const int cc = (off >> 4) & 15;
            kreg[i] = *(const int4*)((const char*)(Kg + (size_t)(t * 64 + row) * KVDIM) + cc * 16);
        }
#pragma unroll
        for (int i = 0; i < 4; ++i) {
            const int off = i * 4096 + tid * 16;
            const int row = off >> 7;
            const int cc = (off >> 4) & 7;
            vreg[i] = *(const int4*)((const char*)(Vg + (size_t)row * SS + t * 64) + cc * 16);
        }
    };

#pragma unroll 1
    for (int pj = 0; pj < 2; ++pj) {
        const int j = pj ? (15 - jj) : jj;
        const int q0 = j * 128;
        const int nt = 2 * j + 2;

        bf16x8 qf[2][4];
#pragma unroll
        for (int m = 0; m < 2; ++m) {
            const int qrow = q0 + w * 32 + m * 16 + l15;
            const bf16* qb = Qb + ((size_t)(b * SS + qrow) << 12) + h * HD + l4 * 8;
#pragma unroll
            for (int kc = 0; kc < 4; ++kc) qf[m][kc] = *(const bf16x8*)(qb + kc * 32);
        }

        f32x4 o[2][8];
#pragma unroll
        for (int m = 0; m < 2; ++m)
#pragma unroll
            for (int df = 0; df < 8; ++df) o[m][df] = vz;
        float m_run[2][4], l_run[2][4];
#pragma unroll
        for (int m = 0; m < 2; ++m)
#pragma unroll
            for (int r = 0; r < 4; ++r) { m_run[m][r] = -1e30f; l_run[m][r] = 0.f; }

        issue_kv(0);

        for (int t = 0; t < nt; ++t) {
            __syncthreads();
#pragma unroll
            for (int i = 0; i < 4; ++i) {
                const int off = i * 4096 + tid * 16;
                const int row = off >> 8;
                const int cc = (off >> 4) & 15;
                const int lc = cc ^ (row & 7);
                *(int4*)((char*)Ks + row * 256 + lc * 16) = kreg[i];
            }
#pragma unroll
            for (int i = 0; i < 4; ++i) {
                const int off = i * 4096 + tid * 16;
                const int row = off >> 7;
                const int cc = (off >> 4) & 7;
                const int lc = cc ^ (row & 7);
                *(int4*)((char*)Vs + row * 128 + lc * 16) = vreg[i];
            }
            __syncthreads();

            if (t + 1 < nt) issue_kv(t + 1);

            f32x4 sa[2][4];
#pragma unroll
            for (int m = 0; m < 2; ++m)
#pragma unroll
                for (int n = 0; n < 4; ++n) sa[m][n] = vz;
            __builtin_amdgcn_s_setprio(1);
#pragma unroll
            for (int kc = 0; kc < 4; ++kc)
#pragma unroll
                for (int n = 0; n < 4; ++n) {
                    const int krow = n * 16 + l15;
                    const int cc = kc * 4 + l4;
                    const bf16x8 kf =
                        *(const bf16x8*)((const char*)Ks + (krow << 8) + ((cc ^ (krow & 7)) << 4));
                    sa[0][n] = MFMA16(qf[0][kc], kf, sa[0][n]);
                    sa[1][n] = MFMA16(qf[1][kc], kf, sa[1][n]);
                }
            __builtin_amdgcn_s_setprio(0);

            if (t >= 2 * j) {
#pragma unroll
                for (int m = 0; m < 2; ++m)
#pragma unroll
                    for (int n = 0; n < 4; ++n)
#pragma unroll
                        for (int r = 0; r < 4; ++r) {
                            const int col = t * 64 + n * 16 + l15;
                            const int qr = q0 + w * 32 + m * 16 + l4 * 4 + r;
                            if (col > qr) sa[m][n][r] = -1e30f;
                        }
            }

#pragma unroll
            for (int m = 0; m < 2; ++m)
#pragma unroll
                for (int r = 0; r < 4; ++r) {
                    float mx = fmaxf(fmaxf(sa[m][0][r], sa[m][1][r]),
                                     fmaxf(sa[m][2][r], sa[m][3][r]));
#pragma unroll
                    for (int mk = 1; mk <= 8; mk <<= 1) mx = fmaxf(mx, __shfl_xor(mx, mk));
                    const float mn = fmaxf(m_run[m][r], mx);
                    const float alpha = fexp2(m_run[m][r] - mn);
                    m_run[m][r] = mn;
                    float rs = 0.f;
#pragma unroll
                    for (int n = 0; n < 4; ++n) {
                        const float p = fexp2(sa[m][n][r] - mn);
                        sa[m][n][r] = p;
                        rs += p;
                    }
#pragma unroll
                    for (int mk = 1; mk <= 8; mk <<= 1) rs += __shfl_xor(rs, mk);
                    l_run[m][r] = l_run[m][r] * alpha + rs;
#pragma unroll
                    for (int df = 0; df < 8; ++df) o[m][df][r] *= alpha;
                }

#pragma unroll
            for (int m = 0; m < 2; ++m)
#pragma unroll
                for (int n = 0; n < 4; ++n)
#pragma unroll
                    for (int r = 0; r < 4; ++r)
                        Ps[w][(m * 16 + l4 * 4 + r) * 88 + n * 16 + l15] = (bf16)sa[m][n][r];

            bf16x8 pf0[2], pf1[2];
#pragma unroll
            for (int ks = 0; ks < 2; ++ks) {
                pf0[ks] = *(const bf16x8*)(&Ps[w][l15 * 88 + ks * 32 + l4 * 8]);
                pf1[ks] = *(const bf16x8*)(&Ps[w][(16 + l15) * 88 + ks * 32 + l4 * 8]);
            }

            __builtin_amdgcn_s_setprio(1);
#pragma unroll
            for (int df = 0; df < 8; ++df)
#pragma unroll
                for (int ks = 0; ks < 2; ++ks) {
                    const int vrow = df * 16 + l15;
                    const int cc = ks * 4 + l4;
                    const bf16x8 vf =
                        *(const bf16x8*)((const char*)Vs + (vrow << 7) + ((cc ^ (vrow & 7)) << 4));
                    o[0][df] = MFMA16(pf0[ks], vf, o[0][df]);
                    o[1][df] = MFMA16(pf1[ks], vf, o[1][df]);
                }
            __builtin_amdgcn_s_setprio(0);
        }

#pragma unroll
        for (int m = 0; m < 2; ++m)
#pragma unroll
            for (int r = 0; r < 4; ++r) {
                const float inv = 1.f / l_run[m][r];
                const size_t row = (size_t)(b * SS + q0 + w * 32 + m * 16 + l4 * 4 + r);
#pragma unroll
                for (int df = 0; df < 8; ++df)
                    Ob[(row << 12) + h * HD + df * 16 + l15] = (bf16)(o[m][df][r] * inv);
            }
    }
}

// ---------------- launcher ----------------
extern "C" void kernel_launch(void* const* d_in, const int* in_sizes, int n_in,
                              void* d_out, int out_size, void* d_ws, size_t ws_size,
                              hipStream_t stream) {
    const float* x    = (const float*)d_in[0];
    const float* fc   = (const float*)d_in[1];
    const float* wqkv = (const float*)d_in[2];
    const float* wo   = (const float*)d_in[3];

    char* wsp = (char*)d_ws;
    const size_t MB = (size_t)1 << 20;
    bf16* xb    = (bf16*)(wsp);              // 32MB
    bf16* wqkvT = (bf16*)(wsp + 32 * MB);    // 48MB
    bf16* woT   = (bf16*)(wsp + 32 * MB);    // 32MB (aliases wqkvT; written after gemm_qkv)
    bf16* Qb    = (bf16*)(wsp + 80 * MB);    // 32MB
    bf16* Kb    = (bf16*)(wsp + 112 * MB);   //  8MB
    bf16* VTb   = (bf16*)(wsp + 120 * MB);   //  8MB
    bf16* Ab    = (bf16*)(wsp);              // attn out bf16 (aliases xb)
    float* out  = (float*)d_out;

    k_cvt_x<<<8192, 256, 0, stream>>>(x, xb);
    k_tr_cvt<<<dim3(NQKV / 64, DD / 64), 256, 0, stream>>>(wqkv, wqkvT, DD, NQKV);
    k_gemm_qkv<<<dim3(NQKV / 256, (BB * SS) / 256), 512, 0, stream>>>(xb, wqkvT, fc, Qb, Kb, VTb);
    k_tr_cvt<<<dim3(DD / 64, QDIM / 64), 256, 0, stream>>>(wo, woT, QDIM, DD);
    k_attn<<<dim3(8, NH, BB), 256, 0, stream>>>(Qb, Kb, VTb, Ab);
    k_gemm_out<<<dim3(DD / 256, (BB * SS) / 256), 512, 0, stream>>>(Ab, woT, out);
}